// Round 6
// baseline (280.606 us; speedup 1.0000x reference)
//
#include <hip/hip_runtime.h>

#define TEN 10

// ---------------------------------------------------------------------------
// Phase A: 5 lanes per chunk, COLUMN ownership (R5 structure). Lane sub owns
// columns j0=2*sub, j1=2*sub+1 of W and M. P-slice p[c][k][a] = P[k][a][j]
// (200 floats) is PINNED to VGPRs with empty asm "+v" constraints: R1-R5
// evidence (VGPR_Count 96..148 << live set, FETCH flat, VALUBusy ~47%) shows
// LLVM sinks the loop-invariant P loads into the loop under pressure,
// re-issuing ~200 L1 loads per step. The asm makes each value an opaque
// producer -> no remat; worst case is scratch spill (visible in WRITE_SIZE).
// W-build is fused into the M-update per column a (w pair computed right
// before its 20 consuming FMAs) to cut ~20 live registers.
// LDS: M col-major, col stride 12 floats, slot stride 132 floats.
// 12 chunks/wave, 48/block, grid=256 (1 block/CU, 1 wave/SIMD, 512-reg pool).
// ---------------------------------------------------------------------------
__global__ __attribute__((amdgpu_flat_work_group_size(256, 256),
                          amdgpu_waves_per_eu(1, 1)))
void automaton_chunks(const float* __restrict__ x, const float* __restrict__ P,
                      float* __restrict__ outBlk, long long T, int C)
{
    // main loop: 48 slots * 132 floats = 6336. tree: T0=48*120 @0, T1 @5760.
    __shared__ __align__(16) float lds[8704];

    const int tid  = threadIdx.x;
    const int wave = tid >> 6;
    const int lane = tid & 63;
    const int grp  = lane / 5;        // 0..11 active, 12 => idle lanes 60..63
    const int sub  = lane % 5;
    const bool active = (grp < 12);
    const int cib  = wave * 12 + grp; // chunk within block 0..47
    const int j0 = 2 * sub, j1 = j0 + 1;

    float p[2][TEN][TEN];             // p[c][k][a] = P[k][a][2sub+c]
    float m[TEN][2];                  // own columns of M
    long long Lc = 0;
    const float2* xp = nullptr;
    float* slot = lds + (active ? cib : 0) * 132;

    if (active) {
        const long long chunk = (long long)blockIdx.x * 48 + cib;
        const long long s0 = chunk * T / C;
        const long long s1 = (chunk + 1) * T / C;
        Lc = s1 - s0;
        xp = reinterpret_cast<const float2*>(x) + s0 * 5;
#pragma unroll
        for (int k = 0; k < TEN; ++k)
#pragma unroll
            for (int a = 0; a < TEN; ++a) {
                const float2 v = *reinterpret_cast<const float2*>(P + k * 100 + a * TEN + j0);
                p[0][k][a] = v.x;
                p[1][k][a] = v.y;
            }
        // PIN: opaque producer per element -> compiler cannot re-load from
        // global inside the loop (the R1-R5 silent degradation).
#pragma unroll
        for (int k = 0; k < TEN; ++k)
#pragma unroll
            for (int a = 0; a < TEN; ++a)
                asm volatile("" : "+v"(p[0][k][a]), "+v"(p[1][k][a]));
#pragma unroll
        for (int r = 0; r < TEN; ++r) {
            m[r][0] = (r == j0) ? 1.0f : 0.0f;
            m[r][1] = (r == j1) ? 1.0f : 0.0f;
        }
    }

    float2 nx0, nx1, nx2, nx3, nx4;
    if (active) { nx0 = xp[0]; nx1 = xp[1]; nx2 = xp[2]; nx3 = xp[3]; nx4 = xp[4]; xp += 5; }

    if (active) {
#pragma unroll 1
        for (long long s = 0; s < Lc; ++s) {
            const float xv[TEN] = {nx0.x, nx0.y, nx1.x, nx1.y, nx2.x,
                                   nx2.y, nx3.x, nx3.y, nx4.x, nx4.y};
            if (s + 1 < Lc) {
                nx0 = xp[0]; nx1 = xp[1]; nx2 = xp[2]; nx3 = xp[3]; nx4 = xp[4];
                xp += 5;
            }

            // 1) publish own columns of M_t (col c at offset (2sub+c)*12)
            {
                float* c0 = slot + j0 * 12;
                reinterpret_cast<float4*>(c0)[0] = make_float4(m[0][0], m[1][0], m[2][0], m[3][0]);
                reinterpret_cast<float4*>(c0)[1] = make_float4(m[4][0], m[5][0], m[6][0], m[7][0]);
                reinterpret_cast<float2*>(c0 + 8)[0] = make_float2(m[8][0], m[9][0]);
                float* c1 = slot + j1 * 12;
                reinterpret_cast<float4*>(c1)[0] = make_float4(m[0][1], m[1][1], m[2][1], m[3][1]);
                reinterpret_cast<float4*>(c1)[1] = make_float4(m[4][1], m[5][1], m[6][1], m[7][1]);
                reinterpret_cast<float2*>(c1 + 8)[0] = make_float2(m[8][1], m[9][1]);
            }
            __builtin_amdgcn_wave_barrier();   // write -> read order (in-order DS pipe)

            // 2) fused per-column: read M_t[:,a], build W[a][j0/j1] on the fly,
            //    rank-1 accumulate into mn. One 400B LDS read per step serves
            //    400 FMA; w-pair computed just-in-time (no w arrays live).
            float mn[TEN][2];
#pragma unroll
            for (int r = 0; r < TEN; ++r) { mn[r][0] = 0.0f; mn[r][1] = 0.0f; }
#pragma unroll
            for (int a = 0; a < TEN; ++a) {
                const float4 v0 = reinterpret_cast<const float4*>(slot + a * 12)[0];
                const float4 v1 = reinterpret_cast<const float4*>(slot + a * 12)[1];
                const float2 v2 = reinterpret_cast<const float2*>(slot + a * 12 + 8)[0];
                float w0a = xv[0] * p[0][0][a];
                float w1a = xv[0] * p[1][0][a];
#pragma unroll
                for (int k = 1; k < TEN; ++k) {
                    w0a = fmaf(xv[k], p[0][k][a], w0a);
                    w1a = fmaf(xv[k], p[1][k][a], w1a);
                }
                const float ca[TEN] = {v0.x, v0.y, v0.z, v0.w, v1.x, v1.y, v1.z, v1.w, v2.x, v2.y};
#pragma unroll
                for (int r = 0; r < TEN; ++r) {
                    mn[r][0] = fmaf(ca[r], w0a, mn[r][0]);
                    mn[r][1] = fmaf(ca[r], w1a, mn[r][1]);
                }
            }
#pragma unroll
            for (int r = 0; r < TEN; ++r) { m[r][0] = mn[r][0]; m[r][1] = mn[r][1]; }
            __builtin_amdgcn_wave_barrier();   // reads before next step's writes
        }
    }

    // ---- in-block ordered tree: 48 chunk matrices -> 1 --------------------
    __syncthreads();                  // main-loop LDS region now dead
    if (active) {
        // stage own columns into ROW-major tree slot cib (stride 120, rows 12)
        float* t = lds + cib * 120;
#pragma unroll
        for (int r = 0; r < TEN; ++r) {
            t[r * 12 + j0] = m[r][0];
            t[r * 12 + j1] = m[r][1];
        }
    }
    __syncthreads();

    // thread-per-row tree products: 48 -> 24 -> 12 -> 6 -> 3 (ping-pong)
    {
        const float* src = lds;
        float* dst = lds + 5760;
        int n = 48;
        while (n > 3) {
            const int np = n >> 1;
            const int pI = tid / TEN;
            const int r  = tid % TEN;
            if (pI < np) {
                const float* A = src + (2 * pI) * 120;
                const float* B = src + (2 * pI + 1) * 120;
                float ar[TEN];
#pragma unroll
                for (int j = 0; j < TEN; ++j) ar[j] = A[r * 12 + j];
                float c[TEN] = {0, 0, 0, 0, 0, 0, 0, 0, 0, 0};
#pragma unroll
                for (int a = 0; a < TEN; ++a) {
                    const float ma = ar[a];
#pragma unroll
                    for (int j = 0; j < TEN; ++j) c[j] = fmaf(ma, B[a * 12 + j], c[j]);
                }
                float* Cq = dst + pI * 120;
#pragma unroll
                for (int j = 0; j < TEN; ++j) Cq[r * 12 + j] = c[j];
            }
            __syncthreads();
            const float* ts = src; src = dst; dst = const_cast<float*>(ts);
            n = np;
        }
        // 3 matrices left in src (== lds). Serial: (M0*M1)*M2 by 10 threads.
        if (tid < TEN) {
            const int r = tid;
            float ar[TEN];
#pragma unroll
            for (int j = 0; j < TEN; ++j) ar[j] = src[r * 12 + j];
            float c[TEN] = {0, 0, 0, 0, 0, 0, 0, 0, 0, 0};
#pragma unroll
            for (int a = 0; a < TEN; ++a) {
                const float ma = ar[a];
#pragma unroll
                for (int j = 0; j < TEN; ++j) c[j] = fmaf(ma, src[120 + a * 12 + j], c[j]);
            }
#pragma unroll
            for (int j = 0; j < TEN; ++j) lds[5760 + r * 12 + j] = c[j];
        }
        __syncthreads();
        if (tid < TEN) {
            const int r = tid;
            float c[TEN] = {0, 0, 0, 0, 0, 0, 0, 0, 0, 0};
#pragma unroll
            for (int a = 0; a < TEN; ++a) {
                const float ma = lds[5760 + r * 12 + a];
#pragma unroll
                for (int j = 0; j < TEN; ++j) c[j] = fmaf(ma, src[240 + a * 12 + j], c[j]);
            }
            float* dr = outBlk + (size_t)blockIdx.x * 100 + r * TEN;
#pragma unroll
            for (int j = 0; j < TEN; ++j) dr[j] = c[j];
        }
    }
}

// ---------------------------------------------------------------------------
// tree64 helper for the final kernel (row-major slots, stride 120).
// Quad row partition {0,1,2},{3,4,5},{6,7,(dup)},{8,9,(dup)}.
// ---------------------------------------------------------------------------
__device__ __forceinline__ void tree64(float* lds, int tid)
{
    const int q     = tid >> 2;
    const int sub   = tid & 3;
    const int rbase = (sub == 3) ? 8 : sub * 3;
    const int r0 = rbase, r1 = rbase + 1;
    const int r2 = (rbase + 2 > 9) ? 9 : rbase + 2;
    const bool w2 = (sub < 2);

    for (int np = 32; np >= 1; np >>= 1) {
        float c[3][TEN];
        if (q < np) {
            const float* A = lds + (2 * q) * 120;
            const float* B = lds + (2 * q + 1) * 120;
            float ar[3][TEN];
#pragma unroll
            for (int t = 0; t < 3; ++t) {
                const int rt = (t == 0) ? r0 : (t == 1) ? r1 : r2;
                const float4 a0 = reinterpret_cast<const float4*>(A + rt * 12)[0];
                const float4 a1 = reinterpret_cast<const float4*>(A + rt * 12)[1];
                const float2 a2 = reinterpret_cast<const float2*>(A + rt * 12 + 8)[0];
                ar[t][0]=a0.x; ar[t][1]=a0.y; ar[t][2]=a0.z; ar[t][3]=a0.w;
                ar[t][4]=a1.x; ar[t][5]=a1.y; ar[t][6]=a1.z; ar[t][7]=a1.w;
                ar[t][8]=a2.x; ar[t][9]=a2.y;
#pragma unroll
                for (int j = 0; j < TEN; ++j) c[t][j] = 0.0f;
            }
#pragma unroll
            for (int a = 0; a < TEN; ++a) {
                const float4 b0 = reinterpret_cast<const float4*>(B + a * 12)[0];
                const float4 b1 = reinterpret_cast<const float4*>(B + a * 12)[1];
                const float2 b2 = reinterpret_cast<const float2*>(B + a * 12 + 8)[0];
                const float br[TEN] = {b0.x,b0.y,b0.z,b0.w,b1.x,b1.y,b1.z,b1.w,b2.x,b2.y};
#pragma unroll
                for (int t = 0; t < 3; ++t) {
                    const float ma = ar[t][a];
#pragma unroll
                    for (int j = 0; j < TEN; ++j) c[t][j] = fmaf(ma, br[j], c[t][j]);
                }
            }
        }
        __syncthreads();
        if (q < np) {
            float* C = lds + q * 120;
#pragma unroll
            for (int t = 0; t < 3; ++t) {
                const int rt = (t == 0) ? r0 : (t == 1) ? r1 : r2;
                if (t < 2 || w2) {
                    float* cr = C + rt * 12;
                    reinterpret_cast<float4*>(cr)[0] = make_float4(c[t][0], c[t][1], c[t][2], c[t][3]);
                    reinterpret_cast<float4*>(cr)[1] = make_float4(c[t][4], c[t][5], c[t][6], c[t][7]);
                    reinterpret_cast<float2*>(cr + 8)[0] = make_float2(c[t][8], c[t][9]);
                }
            }
        }
        __syncthreads();
    }
}

// ---------------------------------------------------------------------------
// Final: one block. 64 quads chain 4 consecutive block-matrices (256 -> 64),
// tree64 -> 1, then apply start/accept.
// ---------------------------------------------------------------------------
__global__ void automaton_final(const float* __restrict__ blkM,
                                const float* __restrict__ start,
                                const float* __restrict__ acc,
                                float* __restrict__ outv)
{
    __shared__ __align__(16) float lds[7680];
    __shared__ float sv[TEN];
    const int tid = threadIdx.x;
    const int q   = tid >> 2;
    const int sub = tid & 3;
    const int rbase = (sub == 3) ? 8 : sub * 3;
    const int rr0 = rbase, rr1 = rbase + 1;
    const int rr2 = (rbase + 2 > 9) ? 9 : rbase + 2;
    const bool w2 = (sub < 2);

    float a[3][TEN];
    {
        const int rr[3] = {rr0, rr1, rr2};
        const float* A0 = blkM + (size_t)(4 * q) * 100;
#pragma unroll
        for (int t = 0; t < 3; ++t) {
            const float2* pp = reinterpret_cast<const float2*>(A0 + rr[t] * TEN);
            const float2 a0 = pp[0], a1 = pp[1], a2 = pp[2], a3 = pp[3], a4 = pp[4];
            a[t][0]=a0.x; a[t][1]=a0.y; a[t][2]=a1.x; a[t][3]=a1.y; a[t][4]=a2.x;
            a[t][5]=a2.y; a[t][6]=a3.x; a[t][7]=a3.y; a[t][8]=a4.x; a[t][9]=a4.y;
        }
    }
#pragma unroll 1
    for (int i = 1; i < 4; ++i) {
        const float* B = blkM + (size_t)(4 * q + i) * 100;
        float c[3][TEN];
#pragma unroll
        for (int t = 0; t < 3; ++t)
#pragma unroll
            for (int j = 0; j < TEN; ++j) c[t][j] = 0.0f;
#pragma unroll
        for (int aa = 0; aa < TEN; ++aa) {
            const float2* br = reinterpret_cast<const float2*>(B + aa * TEN);
            const float2 b0 = br[0], b1 = br[1], b2 = br[2], b3 = br[3], b4 = br[4];
            const float bv[TEN] = {b0.x,b0.y,b1.x,b1.y,b2.x,b2.y,b3.x,b3.y,b4.x,b4.y};
#pragma unroll
            for (int t = 0; t < 3; ++t) {
                const float ma = a[t][aa];
#pragma unroll
                for (int j = 0; j < TEN; ++j) c[t][j] = fmaf(ma, bv[j], c[t][j]);
            }
        }
#pragma unroll
        for (int t = 0; t < 3; ++t)
#pragma unroll
            for (int j = 0; j < TEN; ++j) a[t][j] = c[t][j];
    }
    {
        float* dst = lds + q * 120;
#pragma unroll
        for (int t = 0; t < 3; ++t) {
            const int rt = (t == 0) ? rr0 : (t == 1) ? rr1 : rr2;
            if (t < 2 || w2) {
                float* dr = dst + rt * 12;
                reinterpret_cast<float4*>(dr)[0] = make_float4(a[t][0], a[t][1], a[t][2], a[t][3]);
                reinterpret_cast<float4*>(dr)[1] = make_float4(a[t][4], a[t][5], a[t][6], a[t][7]);
                reinterpret_cast<float2*>(dr + 8)[0] = make_float2(a[t][8], a[t][9]);
            }
        }
    }
    __syncthreads();
    tree64(lds, tid);

    if (tid < TEN) {
        const int j = tid;
        float v = 0.0f;
#pragma unroll
        for (int r = 0; r < TEN; ++r) v = fmaf(start[r], lds[r * 12 + j], v);
        sv[j] = v;
    }
    __syncthreads();
    if (tid == 0) {
        float o0 = 0.0f, o1 = 0.0f;
#pragma unroll
        for (int j = 0; j < TEN; ++j) {
            o0 = fmaf(sv[j], acc[2 * j + 0], o0);
            o1 = fmaf(sv[j], acc[2 * j + 1], o1);
        }
        outv[0] = o0;
        outv[1] = o1;
    }
}

extern "C" void kernel_launch(void* const* d_in, const int* in_sizes, int n_in,
                              void* d_out, int out_size, void* d_ws, size_t ws_size,
                              hipStream_t stream)
{
    const float* x     = (const float*)d_in[0];
    const float* P     = (const float*)d_in[1];
    const float* start = (const float*)d_in[2];
    const float* acc   = (const float*)d_in[3];
    float* out         = (float*)d_out;

    const long long T = (long long)in_sizes[0] / TEN;  // 2,097,152 steps
    const int C = 12288;                               // 48 chunks x 256 blocks

    float* blkM = (float*)d_ws;                        // [256][10][10]

    automaton_chunks<<<256, 256, 0, stream>>>(x, P, blkM, T, C);
    automaton_final<<<1, 256, 0, stream>>>(blkM, start, acc, out);
}